// Round 5
// baseline (295.908 us; speedup 1.0000x reference)
//
#include <hip/hip_runtime.h>

// ---------------------------------------------------------------------------
// Problem constants
//   B=16, C=512, H=W=32 -> T=1024, HEADS=8, HD=64, pairs F=32
// ---------------------------------------------------------------------------

typedef __bf16 bf16x8 __attribute__((ext_vector_type(8)));
typedef float  f32x4  __attribute__((ext_vector_type(4)));

__device__ __forceinline__ f32x4 mfma16(bf16x8 a, bf16x8 b, f32x4 c) {
    return __builtin_amdgcn_mfma_f32_16x16x32_bf16(a, b, c, 0, 0, 0);
}

// async 16B global -> LDS (dest = wave-uniform base + lane*16)
__device__ __forceinline__ void async16(const void* g, void* l) {
    __builtin_amdgcn_global_load_lds(
        (const __attribute__((address_space(1))) void*)g,
        (__attribute__((address_space(3))) void*)l, 16, 0, 0);
}

// raw wait: vmcnt(0), ignore exp/lgkm  (gfx9 encoding: 0x0F70)
#define WAIT_VM0() __builtin_amdgcn_s_waitcnt(0x0F70)

// ---------------------------------------------------------------------------
// 1) weight conversion fp32 -> bf16
// ---------------------------------------------------------------------------
__global__ void k_convert_w(const float* __restrict__ wq, const float* __restrict__ wo,
                            __bf16* __restrict__ wqb, __bf16* __restrict__ wob) {
    int i = blockIdx.x * 256 + threadIdx.x;          // grid covers 786432
    if (i < 3 * 512 * 512) wqb[i] = (__bf16)wq[i];
    if (i < 512 * 512)     wob[i] = (__bf16)wo[i];
}

// ---------------------------------------------------------------------------
// 2) x [B][C][T] fp32  ->  xt [B*T][C] bf16   (LDS tile transpose)
// ---------------------------------------------------------------------------
__global__ void k_transpose_x(const float* __restrict__ x, __bf16* __restrict__ xt) {
    __shared__ float tile[32][33];
    const int b  = blockIdx.z;
    const int c0 = blockIdx.y * 32;
    const int t0 = blockIdx.x * 32;
    const int tx = threadIdx.x, ty = threadIdx.y;    // (32, 8)
    const float* xp = x + ((size_t)b * 512 + c0) * 1024 + t0;
#pragma unroll
    for (int j = 0; j < 4; j++)
        tile[ty + j * 8][tx] = xp[(ty + j * 8) * 1024 + tx];
    __syncthreads();
    __bf16* xo = xt + ((size_t)b * 1024 + t0) * 512 + c0;
#pragma unroll
    for (int j = 0; j < 4; j++)
        xo[(ty + j * 8) * 512 + tx] = (__bf16)tile[tx][ty + j * 8];
}

// ---------------------------------------------------------------------------
// 3) QKV GEMM 16384x1536x512 + fused bias + SO(2) rotation + head split.
//    BK=64, XOR-swizzled global_load_lds staging (0 bank conflicts, R3),
//    DOUBLE-BUFFERED 1-barrier pipeline: DMA of tile t+1 overlaps compute
//    of tile t; raw s_waitcnt vmcnt(0) + s_barrier (m139 pattern) instead of
//    __syncthreads so prefetch stays in flight across the barrier.
// ---------------------------------------------------------------------------
__global__ __launch_bounds__(256) void k_gemm_qkv(
        const __bf16* __restrict__ A, const __bf16* __restrict__ W,
        const float* __restrict__ bias,
        const float* __restrict__ matq, const float* __restrict__ matk,
        const float* __restrict__ matv,
        __bf16* __restrict__ qd, __bf16* __restrict__ kd, __bf16* __restrict__ vtd)
{
    __shared__ __bf16 As[2][128][64];   // 2 x 16 KB
    __shared__ __bf16 Bs[2][128][64];
    const int tid = threadIdx.x;
    const int m0 = blockIdx.x * 128;
    const int n0 = blockIdx.y * 128;
    const int lane = tid & 63, w = tid >> 6;
    const int ln = lane & 15, quad = lane >> 4;
    const int wm = (w >> 1) * 64, wn = (w & 1) * 64;

    const int srow = lane >> 3;                       // 0..7
    const int scol = (((lane & 7) ^ srow) * 8);       // xor chunk swizzle

    f32x4 acc[4][4] = {};

    // stage tile (k0) into buffer buf: 8 DMA insts per wave
#define STAGE(buf, k0)                                                          \
    _Pragma("unroll")                                                           \
    for (int j = 0; j < 4; j++) {                                               \
        int r = w * 32 + j * 8;                                                 \
        async16(&A[(size_t)(m0 + r + srow) * 512 + (k0) + scol], &As[buf][r][0]);\
        async16(&W[(size_t)(n0 + r + srow) * 512 + (k0) + scol], &Bs[buf][r][0]);\
    }

    STAGE(0, 0)
#pragma unroll
    for (int t = 0; t < 8; t++) {
        WAIT_VM0();                       // my tile-t DMAs done (only ones in flight)
        __builtin_amdgcn_s_barrier();     // all waves' tile-t DMAs done; buf[1-cur] free
        if (t < 7) { STAGE((t + 1) & 1, (t + 1) * 64) }
        const int cur = t & 1;
#pragma unroll
        for (int h = 0; h < 2; h++) {
            bf16x8 af[4], wf[4];
#pragma unroll
            for (int mi = 0; mi < 4; mi++)
                af[mi] = *(const bf16x8*)&As[cur][wm + mi * 16 + ln][(((h * 4 + quad) ^ (ln & 7)) * 8)];
#pragma unroll
            for (int ni = 0; ni < 4; ni++)
                wf[ni] = *(const bf16x8*)&Bs[cur][wn + ni * 16 + ln][(((h * 4 + quad) ^ (ln & 7)) * 8)];
#pragma unroll
            for (int mi = 0; mi < 4; mi++)
#pragma unroll
                for (int ni = 0; ni < 4; ni++)
                    acc[mi][ni] = mfma16(af[mi], wf[ni], acc[mi][ni]);
        }
    }

    // Epilogue: bias, rotation (pair partner = col ^ 8 -> lane ^ 8), split store.
    const int part = n0 >> 9;                         // 0=q 1=k 2=v (uniform per block)
    const float2* matp = (const float2*)(part == 0 ? matq : (part == 1 ? matk : matv));
    const int i_par = (ln >> 3) & 1;                  // hd parity
#pragma unroll
    for (int mi = 0; mi < 4; mi++) {
#pragma unroll
        for (int ni = 0; ni < 4; ni++) {
            int o  = n0 + wn + ni * 16 + ln;          // [0,1536)
            int oc = o & 511;
            int hd = oc >> 3, nh = oc & 7, f = oc >> 4;
            float bias_o = bias[o];
#pragma unroll
            for (int r = 0; r < 4; r++) {
                int n = m0 + wm + mi * 16 + quad * 4 + r;   // token row
                int bb = n >> 10, t = n & 1023;
                float val = acc[mi][ni][r] + bias_o;
                float pr  = __shfl_xor(val, 8);
                float2 mv = matp[(t * 32 + f) * 2 + i_par]; // mat[t][f][i][0..1]
                float e  = i_par ? pr : val;                // even-hd input
                float oo = i_par ? val : pr;                // odd-hd input
                float rv = mv.x * e + mv.y * oo;
                int bh = bb * 8 + nh;
                if (part == 0)      qd [((size_t)bh * 1024 + t) * 64 + hd] = (__bf16)rv;
                else if (part == 1) kd [((size_t)bh * 1024 + t) * 64 + hd] = (__bf16)rv;
                else                vtd[((size_t)bh * 64 + hd) * 1024 + t] = (__bf16)rv;
            }
        }
    }
}

// ---------------------------------------------------------------------------
// 4) Flash attention per (qtile=128 rows, head, batch); s-tile = 64.
//    No-max softmax (scores tiny), deferred l-reduction, fused mat_o rotation.
// ---------------------------------------------------------------------------
__global__ __launch_bounds__(256) void k_attn(
        const __bf16* __restrict__ q, const __bf16* __restrict__ kk,
        const __bf16* __restrict__ vt, const float* __restrict__ mato,
        __bf16* __restrict__ od)
{
    __shared__ __bf16 Ks[64][72];        // [s][d]
    __shared__ __bf16 Vs[64][72];        // [hd][s]  (V pre-transposed in global)
    __shared__ __bf16 Ps[4][32][72];     // per-wave P round-trip C-layout -> A-layout
    const int qt = blockIdx.x, nh = blockIdx.y, b = blockIdx.z;
    const int bh = b * 8 + nh;
    const int tid = threadIdx.x, w = tid >> 6, lane = tid & 63;
    const int ln = lane & 15, quad = lane >> 4;
    const int qr0 = qt * 128 + w * 32;   // this wave's 32 q-rows

    bf16x8 qa[2][2];
#pragma unroll
    for (int mi = 0; mi < 2; mi++)
#pragma unroll
        for (int ki = 0; ki < 2; ki++)
            qa[mi][ki] = *(const bf16x8*)&q[((size_t)bh * 1024 + qr0 + mi * 16 + ln) * 64 + ki * 32 + quad * 8];

    f32x4 oacc[2][4] = {};
    float lr[2][4] = {};                 // per-lane partial row sums

    const float C_EXP = 0.18033688011112042f;  // 0.125 * log2(e)

    for (int st = 0; st < 16; st++) {
        // stage K [64][64] and V^T [64][64]
#pragma unroll
        for (int c = 0; c < 2; c++) {
            int idx = tid + c * 256;                 // 512 chunks each
            int row = idx >> 3, g = (idx & 7) * 8;
            *(bf16x8*)&Ks[row][g] = *(const bf16x8*)&kk[((size_t)bh * 1024 + st * 64 + row) * 64 + g];
            *(bf16x8*)&Vs[row][g] = *(const bf16x8*)&vt[((size_t)bh * 64 + row) * 1024 + st * 64 + g];
        }
        __syncthreads();

        // S = Q K^T  (32 x 64 per wave)
        f32x4 s[2][4] = {};
#pragma unroll
        for (int si = 0; si < 4; si++) {
            bf16x8 kb0 = *(const bf16x8*)&Ks[si * 16 + ln][quad * 8];
            bf16x8 kb1 = *(const bf16x8*)&Ks[si * 16 + ln][32 + quad * 8];
#pragma unroll
            for (int mi = 0; mi < 2; mi++) {
                s[mi][si] = mfma16(qa[mi][0], kb0, s[mi][si]);
                s[mi][si] = mfma16(qa[mi][1], kb1, s[mi][si]);
            }
        }

        // p = exp2(s * C_EXP); per-lane partial sums; P -> wave-private LDS
#pragma unroll
        for (int mi = 0; mi < 2; mi++)
#pragma unroll
            for (int si = 0; si < 4; si++)
#pragma unroll
                for (int r = 0; r < 4; r++) {
                    float p = exp2f(s[mi][si][r] * C_EXP);
                    lr[mi][r] += p;
                    Ps[w][mi * 16 + quad * 4 + r][si * 16 + ln] = (__bf16)p;
                }

        // O += P V
#pragma unroll
        for (int kt = 0; kt < 2; kt++) {
            bf16x8 pa0 = *(const bf16x8*)&Ps[w][ln][kt * 32 + quad * 8];
            bf16x8 pa1 = *(const bf16x8*)&Ps[w][16 + ln][kt * 32 + quad * 8];
#pragma unroll
            for (int ni = 0; ni < 4; ni++) {
                bf16x8 vb = *(const bf16x8*)&Vs[ni * 16 + ln][kt * 32 + quad * 8];
                oacc[0][ni] = mfma16(pa0, vb, oacc[0][ni]);
                oacc[1][ni] = mfma16(pa1, vb, oacc[1][ni]);
            }
        }
        __syncthreads();
    }

    // reduce row sums across the 16 lanes holding each row
    float inv[2][4];
#pragma unroll
    for (int mi = 0; mi < 2; mi++)
#pragma unroll
        for (int r = 0; r < 4; r++) {
            float v = lr[mi][r];
#pragma unroll
            for (int d = 1; d <= 8; d <<= 1) v += __shfl_xor(v, d);
            inv[mi][r] = 1.0f / v;
        }

    // epilogue: *inv, rotate with mat_o (pair = hd^1 -> lane^1), store o_rot
    const float2* mo2 = (const float2*)mato;
#pragma unroll
    for (int mi = 0; mi < 2; mi++) {
#pragma unroll
        for (int ni = 0; ni < 4; ni++) {
            int hd = ni * 16 + ln;
            int f = hd >> 1, ip = ln & 1;
#pragma unroll
            for (int r = 0; r < 4; r++) {
                int t = qr0 + mi * 16 + quad * 4 + r;
                float val = oacc[mi][ni][r] * inv[mi][r];
                float pr  = __shfl_xor(val, 1);
                float2 mv = mo2[(t * 32 + f) * 2 + ip];
                float e  = ip ? pr : val;
                float oo = ip ? val : pr;
                float rv = mv.x * e + mv.y * oo;
                od[((size_t)b * 1024 + t) * 512 + hd * 8 + nh] = (__bf16)rv;
            }
        }
    }
}

// ---------------------------------------------------------------------------
// 5) out-proj GEMM 16384x512x512 + bias, fp32 output [b][o][t]
//    Same double-buffered 1-barrier pipeline as k_gemm_qkv.
// ---------------------------------------------------------------------------
__global__ __launch_bounds__(256) void k_gemm_out(
        const __bf16* __restrict__ A, const __bf16* __restrict__ W,
        const float* __restrict__ bias, float* __restrict__ out)
{
    __shared__ __bf16 As[2][128][64];
    __shared__ __bf16 Bs[2][128][64];
    const int tid = threadIdx.x;
    const int m0 = blockIdx.x * 128;
    const int n0 = blockIdx.y * 128;
    const int lane = tid & 63, w = tid >> 6;
    const int ln = lane & 15, quad = lane >> 4;
    const int wm = (w >> 1) * 64, wn = (w & 1) * 64;
    const int srow = lane >> 3;
    const int scol = (((lane & 7) ^ srow) * 8);

    f32x4 acc[4][4] = {};

    STAGE(0, 0)
#pragma unroll
    for (int t = 0; t < 8; t++) {
        WAIT_VM0();
        __builtin_amdgcn_s_barrier();
        if (t < 7) { STAGE((t + 1) & 1, (t + 1) * 64) }
        const int cur = t & 1;
#pragma unroll
        for (int h = 0; h < 2; h++) {
            bf16x8 af[4], wf[4];
#pragma unroll
            for (int mi = 0; mi < 4; mi++)
                af[mi] = *(const bf16x8*)&As[cur][wm + mi * 16 + ln][(((h * 4 + quad) ^ (ln & 7)) * 8)];
#pragma unroll
            for (int ni = 0; ni < 4; ni++)
                wf[ni] = *(const bf16x8*)&Bs[cur][wn + ni * 16 + ln][(((h * 4 + quad) ^ (ln & 7)) * 8)];
#pragma unroll
            for (int mi = 0; mi < 4; mi++)
#pragma unroll
                for (int ni = 0; ni < 4; ni++)
                    acc[mi][ni] = mfma16(af[mi], wf[ni], acc[mi][ni]);
        }
    }

#pragma unroll
    for (int mi = 0; mi < 4; mi++) {
#pragma unroll
        for (int ni = 0; ni < 4; ni++) {
            int o = n0 + wn + ni * 16 + ln;
            float bias_o = bias[o];
            int n = m0 + wm + mi * 16 + quad * 4;
            int bb = n >> 10, t = n & 1023;
            f32x4 v = acc[mi][ni];
            v[0] += bias_o; v[1] += bias_o; v[2] += bias_o; v[3] += bias_o;
            *(f32x4*)&out[((size_t)bb * 512 + o) * 1024 + t] = v;
        }
    }
}

// ---------------------------------------------------------------------------
extern "C" void kernel_launch(void* const* d_in, const int* in_sizes, int n_in,
                              void* d_out, int out_size, void* d_ws, size_t ws_size,
                              hipStream_t stream) {
    (void)in_sizes; (void)n_in; (void)out_size; (void)ws_size;
    const float* x     = (const float*)d_in[0];
    const float* w_qkv = (const float*)d_in[1];
    const float* b_qkv = (const float*)d_in[2];
    const float* w_o   = (const float*)d_in[3];
    const float* b_o   = (const float*)d_in[4];
    const float* mat_q = (const float*)d_in[5];
    const float* mat_k = (const float*)d_in[6];
    const float* mat_v = (const float*)d_in[7];
    const float* mat_o = (const float*)d_in[8];
    float* out = (float*)d_out;

    char* p = (char*)d_ws;
    __bf16* wqb = (__bf16*)p;  p += (size_t)3 * 512 * 512 * 2;        // 1.5 MB
    __bf16* wob = (__bf16*)p;  p += (size_t)512 * 512 * 2;            // 0.5 MB
    char* xt_base = p;
    __bf16* xt  = (__bf16*)p;  p += (size_t)16384 * 512 * 2;          // 16.8 MB
    __bf16* qd  = (__bf16*)p;  p += (size_t)128 * 1024 * 64 * 2;      // 16.8 MB
    __bf16* kd  = (__bf16*)p;  p += (size_t)128 * 1024 * 64 * 2;      // 16.8 MB
    __bf16* vtd = (__bf16*)p;  p += (size_t)128 * 64 * 1024 * 2;      // 16.8 MB
    __bf16* od  = (__bf16*)xt_base;   // alias: xt dead after k_gemm_qkv

    k_convert_w  <<<dim3(3072),       dim3(256),    0, stream>>>(w_qkv, w_o, wqb, wob);
    k_transpose_x<<<dim3(32, 16, 16), dim3(32, 8),  0, stream>>>(x, xt);
    k_gemm_qkv   <<<dim3(128, 12),    dim3(256),    0, stream>>>(xt, wqb, b_qkv, mat_q, mat_k, mat_v, qd, kd, vtd);
    k_attn       <<<dim3(8, 8, 16),   dim3(256),    0, stream>>>(qd, kd, vtd, mat_o, od);
    k_gemm_out   <<<dim3(128, 4),     dim3(256),    0, stream>>>(od, wob, b_o, out);
}

// Round 6
// 269.401 us; speedup vs baseline: 1.0984x; 1.0984x over previous
//
#include <hip/hip_runtime.h>

// ---------------------------------------------------------------------------
// Problem constants
//   B=16, C=512, H=W=32 -> T=1024, HEADS=8, HD=64, pairs F=32
// ---------------------------------------------------------------------------

typedef __bf16 bf16x8 __attribute__((ext_vector_type(8)));
typedef float  f32x4  __attribute__((ext_vector_type(4)));

__device__ __forceinline__ f32x4 mfma16(bf16x8 a, bf16x8 b, f32x4 c) {
    return __builtin_amdgcn_mfma_f32_16x16x32_bf16(a, b, c, 0, 0, 0);
}

// async 16B global -> LDS (dest = wave-uniform base + lane*16)
__device__ __forceinline__ void async16(const void* g, void* l) {
    __builtin_amdgcn_global_load_lds(
        (const __attribute__((address_space(1))) void*)g,
        (__attribute__((address_space(3))) void*)l, 16, 0, 0);
}

// ---------------------------------------------------------------------------
// 1) weight conversion fp32 -> bf16
// ---------------------------------------------------------------------------
__global__ void k_convert_w(const float* __restrict__ wq, const float* __restrict__ wo,
                            __bf16* __restrict__ wqb, __bf16* __restrict__ wob) {
    int i = blockIdx.x * 256 + threadIdx.x;          // grid covers 786432
    if (i < 3 * 512 * 512) wqb[i] = (__bf16)wq[i];
    if (i < 512 * 512)     wob[i] = (__bf16)wo[i];
}

// ---------------------------------------------------------------------------
// 2) x [B][C][T] fp32  ->  xt [B*T][C] bf16   (LDS tile transpose)
// ---------------------------------------------------------------------------
__global__ void k_transpose_x(const float* __restrict__ x, __bf16* __restrict__ xt) {
    __shared__ float tile[32][33];
    const int b  = blockIdx.z;
    const int c0 = blockIdx.y * 32;
    const int t0 = blockIdx.x * 32;
    const int tx = threadIdx.x, ty = threadIdx.y;    // (32, 8)
    const float* xp = x + ((size_t)b * 512 + c0) * 1024 + t0;
#pragma unroll
    for (int j = 0; j < 4; j++)
        tile[ty + j * 8][tx] = xp[(ty + j * 8) * 1024 + tx];
    __syncthreads();
    __bf16* xo = xt + ((size_t)b * 1024 + t0) * 512 + c0;
#pragma unroll
    for (int j = 0; j < 4; j++)
        xo[(ty + j * 8) * 512 + tx] = (__bf16)tile[tx][ty + j * 8];
}

// ---------------------------------------------------------------------------
// 3) QKV GEMM 16384x1536x512 + fused bias + SO(2) rotation + head split.
//    Tile 128m x 64n, BK=64, single-buffer staging (R4 dbuf regressed:
//    occupancy loss > pipeline gain at this size). XOR chunk swizzle keeps
//    fragment reads conflict-free (0 measured, R3). 4 waves split M: each
//    wave 32m x 64n, acc[2][4]. Grid 128x24 = 3072 blocks (~5-6/CU resident)
//    so cross-block TLP hides the per-iteration DMA latency.
// ---------------------------------------------------------------------------
__global__ __launch_bounds__(256) void k_gemm_qkv(
        const __bf16* __restrict__ A, const __bf16* __restrict__ W,
        const float* __restrict__ bias,
        const float* __restrict__ matq, const float* __restrict__ matk,
        const float* __restrict__ matv,
        __bf16* __restrict__ qd, __bf16* __restrict__ kd, __bf16* __restrict__ vtd)
{
    __shared__ __bf16 As[128][64];   // 16 KB
    __shared__ __bf16 Bs[64][64];    //  8 KB
    const int tid = threadIdx.x;
    const int m0 = blockIdx.x * 128;
    const int n0 = blockIdx.y * 64;
    const int lane = tid & 63, w = tid >> 6;
    const int ln = lane & 15, quad = lane >> 4;
    const int wm = w * 32;

    const int srow = lane >> 3;                       // 0..7
    const int scol = (((lane & 7) ^ srow) * 8);       // xor chunk swizzle

    f32x4 acc[2][4] = {};

    for (int k0 = 0; k0 < 512; k0 += 64) {
#pragma unroll
        for (int j = 0; j < 4; j++) {                 // A: wave stages its own 32 rows
            int r = w * 32 + j * 8;
            async16(&A[(size_t)(m0 + r + srow) * 512 + k0 + scol], &As[r][0]);
        }
#pragma unroll
        for (int j = 0; j < 2; j++) {                 // W: 64 rows split across waves
            int r = w * 16 + j * 8;
            async16(&W[(size_t)(n0 + r + srow) * 512 + k0 + scol], &Bs[r][0]);
        }
        __syncthreads();
#pragma unroll
        for (int h = 0; h < 2; h++) {
            bf16x8 af[2], wf[4];
#pragma unroll
            for (int mi = 0; mi < 2; mi++)
                af[mi] = *(const bf16x8*)&As[wm + mi * 16 + ln][(((h * 4 + quad) ^ (ln & 7)) * 8)];
#pragma unroll
            for (int ni = 0; ni < 4; ni++)
                wf[ni] = *(const bf16x8*)&Bs[ni * 16 + ln][(((h * 4 + quad) ^ (ln & 7)) * 8)];
#pragma unroll
            for (int mi = 0; mi < 2; mi++)
#pragma unroll
                for (int ni = 0; ni < 4; ni++)
                    acc[mi][ni] = mfma16(af[mi], wf[ni], acc[mi][ni]);
        }
        __syncthreads();
    }

    // Epilogue: bias, rotation (pair partner = col ^ 8 -> lane ^ 8), split store.
    const int part = n0 >> 9;                         // 0=q 1=k 2=v (uniform per block)
    const float2* matp = (const float2*)(part == 0 ? matq : (part == 1 ? matk : matv));
    const int i_par = (ln >> 3) & 1;                  // hd parity
#pragma unroll
    for (int mi = 0; mi < 2; mi++) {
#pragma unroll
        for (int ni = 0; ni < 4; ni++) {
            int o  = n0 + ni * 16 + ln;               // [0,1536)
            int oc = o & 511;
            int hd = oc >> 3, nh = oc & 7, f = oc >> 4;
            float bias_o = bias[o];
#pragma unroll
            for (int r = 0; r < 4; r++) {
                int n = m0 + wm + mi * 16 + quad * 4 + r;   // token row
                int bb = n >> 10, t = n & 1023;
                float val = acc[mi][ni][r] + bias_o;
                float pr  = __shfl_xor(val, 8);
                float2 mv = matp[(t * 32 + f) * 2 + i_par]; // mat[t][f][i][0..1]
                float e  = i_par ? pr : val;                // even-hd input
                float oo = i_par ? val : pr;                // odd-hd input
                float rv = mv.x * e + mv.y * oo;
                int bh = bb * 8 + nh;
                if (part == 0)      qd [((size_t)bh * 1024 + t) * 64 + hd] = (__bf16)rv;
                else if (part == 1) kd [((size_t)bh * 1024 + t) * 64 + hd] = (__bf16)rv;
                else                vtd[((size_t)bh * 64 + hd) * 1024 + t] = (__bf16)rv;
            }
        }
    }
}

// ---------------------------------------------------------------------------
// 4) Flash attention per (qtile=128 rows, head, batch); s-tile = 64.
//    No-max softmax (scores tiny), deferred l-reduction, fused mat_o rotation.
// ---------------------------------------------------------------------------
__global__ __launch_bounds__(256) void k_attn(
        const __bf16* __restrict__ q, const __bf16* __restrict__ kk,
        const __bf16* __restrict__ vt, const float* __restrict__ mato,
        __bf16* __restrict__ od)
{
    __shared__ __bf16 Ks[64][72];        // [s][d]
    __shared__ __bf16 Vs[64][72];        // [hd][s]  (V pre-transposed in global)
    __shared__ __bf16 Ps[4][32][72];     // per-wave P round-trip C-layout -> A-layout
    const int qt = blockIdx.x, nh = blockIdx.y, b = blockIdx.z;
    const int bh = b * 8 + nh;
    const int tid = threadIdx.x, w = tid >> 6, lane = tid & 63;
    const int ln = lane & 15, quad = lane >> 4;
    const int qr0 = qt * 128 + w * 32;   // this wave's 32 q-rows

    bf16x8 qa[2][2];
#pragma unroll
    for (int mi = 0; mi < 2; mi++)
#pragma unroll
        for (int ki = 0; ki < 2; ki++)
            qa[mi][ki] = *(const bf16x8*)&q[((size_t)bh * 1024 + qr0 + mi * 16 + ln) * 64 + ki * 32 + quad * 8];

    f32x4 oacc[2][4] = {};
    float lr[2][4] = {};                 // per-lane partial row sums

    const float C_EXP = 0.18033688011112042f;  // 0.125 * log2(e)

    for (int st = 0; st < 16; st++) {
        // stage K [64][64] and V^T [64][64]
#pragma unroll
        for (int c = 0; c < 2; c++) {
            int idx = tid + c * 256;                 // 512 chunks each
            int row = idx >> 3, g = (idx & 7) * 8;
            *(bf16x8*)&Ks[row][g] = *(const bf16x8*)&kk[((size_t)bh * 1024 + st * 64 + row) * 64 + g];
            *(bf16x8*)&Vs[row][g] = *(const bf16x8*)&vt[((size_t)bh * 64 + row) * 1024 + st * 64 + g];
        }
        __syncthreads();

        // S = Q K^T  (32 x 64 per wave)
        f32x4 s[2][4] = {};
#pragma unroll
        for (int si = 0; si < 4; si++) {
            bf16x8 kb0 = *(const bf16x8*)&Ks[si * 16 + ln][quad * 8];
            bf16x8 kb1 = *(const bf16x8*)&Ks[si * 16 + ln][32 + quad * 8];
#pragma unroll
            for (int mi = 0; mi < 2; mi++) {
                s[mi][si] = mfma16(qa[mi][0], kb0, s[mi][si]);
                s[mi][si] = mfma16(qa[mi][1], kb1, s[mi][si]);
            }
        }

        // p = exp2(s * C_EXP); per-lane partial sums; P -> wave-private LDS
#pragma unroll
        for (int mi = 0; mi < 2; mi++)
#pragma unroll
            for (int si = 0; si < 4; si++)
#pragma unroll
                for (int r = 0; r < 4; r++) {
                    float p = exp2f(s[mi][si][r] * C_EXP);
                    lr[mi][r] += p;
                    Ps[w][mi * 16 + quad * 4 + r][si * 16 + ln] = (__bf16)p;
                }

        // O += P V
#pragma unroll
        for (int kt = 0; kt < 2; kt++) {
            bf16x8 pa0 = *(const bf16x8*)&Ps[w][ln][kt * 32 + quad * 8];
            bf16x8 pa1 = *(const bf16x8*)&Ps[w][16 + ln][kt * 32 + quad * 8];
#pragma unroll
            for (int ni = 0; ni < 4; ni++) {
                bf16x8 vb = *(const bf16x8*)&Vs[ni * 16 + ln][kt * 32 + quad * 8];
                oacc[0][ni] = mfma16(pa0, vb, oacc[0][ni]);
                oacc[1][ni] = mfma16(pa1, vb, oacc[1][ni]);
            }
        }
        __syncthreads();
    }

    // reduce row sums across the 16 lanes holding each row
    float inv[2][4];
#pragma unroll
    for (int mi = 0; mi < 2; mi++)
#pragma unroll
        for (int r = 0; r < 4; r++) {
            float v = lr[mi][r];
#pragma unroll
            for (int d = 1; d <= 8; d <<= 1) v += __shfl_xor(v, d);
            inv[mi][r] = 1.0f / v;
        }

    // epilogue: *inv, rotate with mat_o (pair = hd^1 -> lane^1), store o_rot
    const float2* mo2 = (const float2*)mato;
#pragma unroll
    for (int mi = 0; mi < 2; mi++) {
#pragma unroll
        for (int ni = 0; ni < 4; ni++) {
            int hd = ni * 16 + ln;
            int f = hd >> 1, ip = ln & 1;
#pragma unroll
            for (int r = 0; r < 4; r++) {
                int t = qr0 + mi * 16 + quad * 4 + r;
                float val = oacc[mi][ni][r] * inv[mi][r];
                float pr  = __shfl_xor(val, 1);
                float2 mv = mo2[(t * 32 + f) * 2 + ip];
                float e  = ip ? pr : val;
                float oo = ip ? val : pr;
                float rv = mv.x * e + mv.y * oo;
                od[((size_t)b * 1024 + t) * 512 + hd * 8 + nh] = (__bf16)rv;
            }
        }
    }
}

// ---------------------------------------------------------------------------
// 5) out-proj GEMM 16384x512x512 + bias, fp32 output [b][o][t]
//    Tile 128x64 (grid 1024 blocks vs 512 at 128x128 -> latency hiding).
// ---------------------------------------------------------------------------
__global__ __launch_bounds__(256) void k_gemm_out(
        const __bf16* __restrict__ A, const __bf16* __restrict__ W,
        const float* __restrict__ bias, float* __restrict__ out)
{
    __shared__ __bf16 As[128][64];
    __shared__ __bf16 Bs[64][64];
    const int tid = threadIdx.x;
    const int m0 = blockIdx.x * 128;
    const int n0 = blockIdx.y * 64;
    const int lane = tid & 63, w = tid >> 6;
    const int ln = lane & 15, quad = lane >> 4;
    const int wm = w * 32;
    const int srow = lane >> 3;
    const int scol = (((lane & 7) ^ srow) * 8);

    f32x4 acc[2][4] = {};

    for (int k0 = 0; k0 < 512; k0 += 64) {
#pragma unroll
        for (int j = 0; j < 4; j++) {
            int r = w * 32 + j * 8;
            async16(&A[(size_t)(m0 + r + srow) * 512 + k0 + scol], &As[r][0]);
        }
#pragma unroll
        for (int j = 0; j < 2; j++) {
            int r = w * 16 + j * 8;
            async16(&W[(size_t)(n0 + r + srow) * 512 + k0 + scol], &Bs[r][0]);
        }
        __syncthreads();
#pragma unroll
        for (int h = 0; h < 2; h++) {
            bf16x8 af[2], wf[4];
#pragma unroll
            for (int mi = 0; mi < 2; mi++)
                af[mi] = *(const bf16x8*)&As[wm + mi * 16 + ln][(((h * 4 + quad) ^ (ln & 7)) * 8)];
#pragma unroll
            for (int ni = 0; ni < 4; ni++)
                wf[ni] = *(const bf16x8*)&Bs[ni * 16 + ln][(((h * 4 + quad) ^ (ln & 7)) * 8)];
#pragma unroll
            for (int mi = 0; mi < 2; mi++)
#pragma unroll
                for (int ni = 0; ni < 4; ni++)
                    acc[mi][ni] = mfma16(af[mi], wf[ni], acc[mi][ni]);
        }
        __syncthreads();
    }

#pragma unroll
    for (int mi = 0; mi < 2; mi++) {
#pragma unroll
        for (int ni = 0; ni < 4; ni++) {
            int o = n0 + ni * 16 + ln;
            float bias_o = bias[o];
            int n = m0 + wm + mi * 16 + quad * 4;
            int bb = n >> 10, t = n & 1023;
            f32x4 v = acc[mi][ni];
            v[0] += bias_o; v[1] += bias_o; v[2] += bias_o; v[3] += bias_o;
            *(f32x4*)&out[((size_t)bb * 512 + o) * 1024 + t] = v;
        }
    }
}

// ---------------------------------------------------------------------------
extern "C" void kernel_launch(void* const* d_in, const int* in_sizes, int n_in,
                              void* d_out, int out_size, void* d_ws, size_t ws_size,
                              hipStream_t stream) {
    (void)in_sizes; (void)n_in; (void)out_size; (void)ws_size;
    const float* x     = (const float*)d_in[0];
    const float* w_qkv = (const float*)d_in[1];
    const float* b_qkv = (const float*)d_in[2];
    const float* w_o   = (const float*)d_in[3];
    const float* b_o   = (const float*)d_in[4];
    const float* mat_q = (const float*)d_in[5];
    const float* mat_k = (const float*)d_in[6];
    const float* mat_v = (const float*)d_in[7];
    const float* mat_o = (const float*)d_in[8];
    float* out = (float*)d_out;

    char* p = (char*)d_ws;
    __bf16* wqb = (__bf16*)p;  p += (size_t)3 * 512 * 512 * 2;        // 1.5 MB
    __bf16* wob = (__bf16*)p;  p += (size_t)512 * 512 * 2;            // 0.5 MB
    char* xt_base = p;
    __bf16* xt  = (__bf16*)p;  p += (size_t)16384 * 512 * 2;          // 16.8 MB
    __bf16* qd  = (__bf16*)p;  p += (size_t)128 * 1024 * 64 * 2;      // 16.8 MB
    __bf16* kd  = (__bf16*)p;  p += (size_t)128 * 1024 * 64 * 2;      // 16.8 MB
    __bf16* vtd = (__bf16*)p;  p += (size_t)128 * 64 * 1024 * 2;      // 16.8 MB
    __bf16* od  = (__bf16*)xt_base;   // alias: xt dead after k_gemm_qkv

    k_convert_w  <<<dim3(3072),       dim3(256),    0, stream>>>(w_qkv, w_o, wqb, wob);
    k_transpose_x<<<dim3(32, 16, 16), dim3(32, 8),  0, stream>>>(x, xt);
    k_gemm_qkv   <<<dim3(128, 24),    dim3(256),    0, stream>>>(xt, wqb, b_qkv, mat_q, mat_k, mat_v, qd, kd, vtd);
    k_attn       <<<dim3(8, 8, 16),   dim3(256),    0, stream>>>(qd, kd, vtd, mat_o, od);
    k_gemm_out   <<<dim3(128, 8),     dim3(256),    0, stream>>>(od, wob, b_o, out);
}